// Round 9
// baseline (162.294 us; speedup 1.0000x reference)
//
#include <hip/hip_runtime.h>

#define D 768
#define CAP 64        // max layer-2 in-edges per target
#define MD1 16        // max in-degree per needed node (real ~2-3)
#define NSLOTMAX 1040 // B + B*CAP (B=16)
#define VROWS 64      // cap on total valid rows (real ~48)
#define QCAP 64       // per-block eager-dot queue
#define NI 24         // i-chunks (768 = 24*32)
#define IC 32
#define NBLK 144
#define NEG 0.2f

struct KArgs {
    const float *x, *ef;
    const int *src, *dst, *goff;
    const float *W1, *We1, *b1, *W2, *We2, *b2;
    const float *al1, *ar1, *ae1, *al2, *ar2, *ae2;
    float* out;
    int E, B, nslot;
    int* bar;                 // 8 ints (4 used), pre-zeroed
    int *cnt, *mcnt, *l2e, *medge, *msrc;
    float *melog, *erj, *elog2, *er2, *v, *h;
};

__device__ __forceinline__ float wave_reduce(float v) {
    #pragma unroll
    for (int o = 32; o > 0; o >>= 1) v += __shfl_down(v, o, 64);
    return v;
}

// arrive-and-spin barrier; slot pre-zeroed each launch; no reuse -> race-free
__device__ __forceinline__ void gbar(int* slot) {
    __syncthreads();
    if (threadIdx.x == 0) {
        __threadfence();
        __hip_atomic_fetch_add(slot, 1, __ATOMIC_ACQ_REL, __HIP_MEMORY_SCOPE_AGENT);
        long t = 0;
        while (__hip_atomic_load(slot, __ATOMIC_ACQUIRE, __HIP_MEMORY_SCOPE_AGENT) < NBLK) {
            __builtin_amdgcn_s_sleep(2);
            if (++t > (1L << 22)) break;   // failsafe: no hang
        }
        __threadfence();
    }
    __syncthreads();
}

__global__ __launch_bounds__(256) void allfused(KArgs a) {
    const int tid = threadIdx.x, bid = blockIdx.x;
    const int wv = tid >> 6, lane = tid & 63;
    const int B = a.B, E = a.E, nslot = a.nslot;

    __shared__ int tg[16];
    __shared__ int tnode[NSLOTMAX], tslot[NSLOTMAX];
    __shared__ int tn, qn;
    __shared__ int qe[QCAP], qs[QCAP], qsl[QCAP], qp[QCAP];
    __shared__ int vl[VROWS], vn_sh, snm[VROWS];
    __shared__ float smatt[VROWS][MD1];
    __shared__ int ssrc[VROWS][MD1], sedge[VROWS][MD1];
    __shared__ float sgS[32][IC], sgE[32][IC];
    __shared__ int se2[16][CAP], sp2[16][CAP], sdeg2[16];
    __shared__ float sw2[16][CAP];

    // ================= phase A: proj v  ||  build l2 lists =================
    {
        int wg = bid * 4 + wv;
        for (int task = wg; task < 4 * D; task += NBLK * 4) {
            int g = task / D, i = task % D;
            const float* W; const float* p1; const float* p2 = nullptr;
            int o1 = 0, o2 = 0;
            switch (g) {
                case 0: W = a.W1;  p1 = a.al1; p2 = a.ar1; o1 = 0;     o2 = D;     break;
                case 1: W = a.We1; p1 = a.ae1;             o1 = 2 * D;             break;
                case 2: W = a.W2;  p1 = a.al2; p2 = a.ar2; o1 = 3 * D; o2 = 4 * D; break;
                default:W = a.We2; p1 = a.ae2;             o1 = 5 * D;             break;
            }
            float s1 = 0.f, s2 = 0.f;
            for (int j = lane; j < D; j += 64) {
                float w = W[(long)i * D + j];
                s1 += w * p1[j];
                if (p2) s2 += w * p2[j];
            }
            #pragma unroll
            for (int o = 32; o > 0; o >>= 1) { s1 += __shfl_down(s1, o, 64); s2 += __shfl_down(s2, o, 64); }
            if (lane == 0) { a.v[o1 + i] = s1; if (p2) a.v[o2 + i] = s2; }
        }
        if (tid < B) tg[tid] = a.goff[tid];
        __syncthreads();
        for (int e = bid * 256 + tid; e < E; e += NBLK * 256) {
            int d = a.dst[e];
            for (int b = 0; b < B; ++b) {
                if (d == tg[b]) {
                    int p = atomicAdd(&a.cnt[b], 1);
                    if (p < CAP) a.l2e[b * CAP + p] = e;
                }
            }
        }
    }
    gbar(a.bar + 0);

    // ===== phase B: node table; er dots + h-init; match + eager dots =======
    {
        if (tid == 0) { tn = 0; qn = 0; }
        __syncthreads();
        for (int s = tid; s < nslot; s += 256) {
            int node = -1; bool valid = false;
            if (s < B) { node = a.goff[s]; valid = true; }
            else { int rb = (s - B) >> 6, i = (s - B) & 63;
                   int cb = a.cnt[rb]; if (cb > CAP) cb = CAP;
                   if (i < cb) { node = a.src[a.l2e[rb * CAP + i]]; valid = true; } }
            if (valid) { int p = atomicAdd(&tn, 1); tnode[p] = node; tslot[p] = s; }
        }
        __syncthreads();
        int M = tn;
        const float* val1 = a.v;
        const float* var1 = a.v + D;
        const float* vae1 = a.v + 2 * D;
        // er dot + h init, one wave per slot
        for (int s = bid * 4 + wv; s < nslot; s += NBLK * 4) {
            int j = -1; bool valid = false;
            if (s < B) { j = a.goff[s]; valid = true; }
            else { int rb = (s - B) >> 6, i = (s - B) & 63;
                   int cb = a.cnt[rb]; if (cb > CAP) cb = CAP;
                   if (i < cb) { j = a.src[a.l2e[rb * CAP + i]]; valid = true; } }
            if (valid) {
                float acc = 0.f;
                for (int c = lane; c < D; c += 64) acc += a.x[(long)j * D + c] * var1[c];
                acc = wave_reduce(acc);
                if (lane == 0) a.erj[s] = acc;
                for (int c = lane; c < D; c += 64)
                    a.h[(long)s * D + c] = a.x[(long)j * D + c] + a.b1[c];
            }
        }
        // match scan + queue eager dots
        for (int e = bid * 256 + tid; e < E; e += NBLK * 256) {
            int d = a.dst[e];
            for (int c = 0; c < M; ++c) {
                if (tnode[c] == d) {
                    int sl = tslot[c];
                    int p = atomicAdd(&a.mcnt[sl], 1);
                    if (p < MD1) {
                        int sr = a.src[e];
                        a.medge[sl * MD1 + p] = e;
                        a.msrc[sl * MD1 + p] = sr;
                        int qq = atomicAdd(&qn, 1);
                        if (qq < QCAP) { qe[qq] = e; qs[qq] = sr; qsl[qq] = sl; qp[qq] = p; }
                        else {
                            float acc = 0.f;
                            for (int cc = 0; cc < D; ++cc)
                                acc += a.x[(long)sr * D + cc] * val1[cc]
                                     + a.ef[(long)e * D + cc] * vae1[cc];
                            a.melog[sl * MD1 + p] = acc;
                        }
                    }
                }
            }
        }
        __syncthreads();
        int nq = qn; if (nq > QCAP) nq = QCAP;
        for (int m = wv; m < nq; m += 4) {
            int e = qe[m], sr = qs[m];
            float acc = 0.f;
            for (int c = lane; c < D; c += 64)
                acc += a.x[(long)sr * D + c] * val1[c] + a.ef[(long)e * D + c] * vae1[c];
            acc = wave_reduce(acc);
            if (lane == 0) a.melog[qsl[m] * MD1 + qp[m]] = acc;
        }
    }
    gbar(a.bar + 1);

    // ========== phase C: softmax1 (redundant) + row-split GEMM1 ============
    {
        // deterministic valid-row list (slot order) via wave-0 ballot
        if (tid < 64) {
            int base = 0;
            for (int s0 = 0; s0 < nslot; s0 += 64) {
                int s = s0 + tid;
                bool valid = false;
                if (s < B) valid = true;
                else if (s < nslot) {
                    int rb = (s - B) >> 6, i = (s - B) & 63;
                    int cb = a.cnt[rb]; if (cb > CAP) cb = CAP;
                    valid = i < cb;
                }
                unsigned long long mb = __ballot(valid);
                if (valid) {
                    int ci = base + __popcll(mb & ((1ULL << tid) - 1));
                    if (ci < VROWS) vl[ci] = s;
                }
                base += __popcll(mb);
            }
            if (tid == 0) vn_sh = base < VROWS ? base : VROWS;
        }
        __syncthreads();
        int vn = vn_sh;
        if (tid < vn) {  // per-row: load, sort by edge id, leaky+softmax
            int s = vl[tid];
            int nm = a.mcnt[s]; if (nm > MD1) nm = MD1;
            snm[tid] = nm;
            for (int k = 0; k < nm; ++k) {
                sedge[tid][k] = a.medge[s * MD1 + k];
                ssrc[tid][k]  = a.msrc[s * MD1 + k];
                smatt[tid][k] = a.melog[s * MD1 + k];
            }
            for (int a_ = 1; a_ < nm; ++a_) {
                int ke = sedge[tid][a_], ks = ssrc[tid][a_]; float kl = smatt[tid][a_];
                int b = a_ - 1;
                while (b >= 0 && sedge[tid][b] > ke) {
                    sedge[tid][b+1] = sedge[tid][b]; ssrc[tid][b+1] = ssrc[tid][b];
                    smatt[tid][b+1] = smatt[tid][b]; --b;
                }
                sedge[tid][b+1] = ke; ssrc[tid][b+1] = ks; smatt[tid][b+1] = kl;
            }
            float er = a.erj[s], mx = -1e30f;
            for (int k = 0; k < nm; ++k) {
                float l = smatt[tid][k] + er;
                l = l >= 0.f ? l : NEG * l;
                smatt[tid][k] = l; mx = fmaxf(mx, l);
            }
            float sum = 0.f;
            for (int k = 0; k < nm; ++k) { float p = expf(smatt[tid][k] - mx); smatt[tid][k] = p; sum += p; }
            float inv = 1.f / sum;
            for (int k = 0; k < nm; ++k) smatt[tid][k] *= inv;
        }
        __syncthreads();
        // task: q = bid%3 (col chunk), iy = (bid/3)%NI (i chunk), rh = bid/72
        int q = bid % 3, iy = (bid / 3) % NI, rh = bid / (3 * NI);
        int half = (vn + 1) >> 1;
        int r0 = rh * half, r1 = r0 + half; if (r1 > vn) r1 = vn;
        int col = q * 256 + tid, i0 = iy * IC;
        int nr = r1 - r0;
        for (int t = tid; t < 2 * nr; t += 256) {  // stage (row, mat) pairs
            int lr = t >> 1, mat = t & 1, r = r0 + lr;
            int nm = snm[r];
            float acc[IC];
            #pragma unroll
            for (int i = 0; i < IC; ++i) acc[i] = 0.f;
            if (mat == 0) {
                for (int k = 0; k < nm; ++k) {
                    const float* p = a.x + (long)ssrc[r][k] * D + i0;
                    float w_ = smatt[r][k];
                    #pragma unroll
                    for (int i = 0; i < IC; ++i) acc[i] += w_ * p[i];
                }
                #pragma unroll
                for (int i = 0; i < IC; ++i) sgS[lr][i] = acc[i];
            } else {
                for (int k = 0; k < nm; ++k) {
                    const float* p = a.ef + (long)sedge[r][k] * D + i0;
                    float w_ = smatt[r][k];
                    #pragma unroll
                    for (int i = 0; i < IC; ++i) acc[i] += w_ * p[i];
                }
                #pragma unroll
                for (int i = 0; i < IC; ++i) sgE[lr][i] = acc[i];
            }
        }
        __syncthreads();
        if (nr > 0) {  // weights loaded after staging to cap VGPR pressure
            float w[IC], we[IC];
            #pragma unroll
            for (int k = 0; k < IC; ++k) {
                w[k]  = a.W1[(long)(i0 + k) * D + col];
                we[k] = a.We1[(long)(i0 + k) * D + col];
            }
            for (int lr = 0; lr < nr; ++lr) {
                float acc = 0.f;
                #pragma unroll
                for (int k = 0; k < IC; ++k) acc += sgS[lr][k] * w[k] + sgE[lr][k] * we[k];
                atomicAdd(&a.h[(long)vl[r0 + lr] * D + col], acc);
            }
        }
    }
    gbar(a.bar + 2);

    // ================= phase D: layer-2 logit dots on relu(h) ==============
    {
        const float* val2 = a.v + 3 * D;
        const float* var2 = a.v + 4 * D;
        const float* vae2 = a.v + 5 * D;
        for (int t = bid * 4 + wv; t < nslot; t += NBLK * 4) {
            if (t < B) {
                const float* hb = a.h + (long)t * D;
                float acc = 0.f;
                for (int c = lane; c < D; c += 64) acc += fmaxf(hb[c], 0.f) * var2[c];
                acc = wave_reduce(acc);
                if (lane == 0) a.er2[t] = acc;
            } else {
                int rb = (t - B) >> 6, i = (t - B) & 63;
                int cb = a.cnt[rb]; if (cb > CAP) cb = CAP;
                if (i < cb) {
                    int e = a.l2e[rb * CAP + i];
                    const float* hs = a.h + (long)t * D;
                    float acc = 0.f;
                    for (int c = lane; c < D; c += 64)
                        acc += fmaxf(hs[c], 0.f) * val2[c] + a.ef[(long)e * D + c] * vae2[c];
                    acc = wave_reduce(acc);
                    if (lane == 0) a.elog2[rb * CAP + i] = acc;
                }
            }
        }
    }
    gbar(a.bar + 3);

    // ============ phase E: softmax2 (redundant, scalar) + GEMM2 ============
    if (bid < 3 * NI) {
        if (tid < B) {  // thread per target: sort + leaky + softmax
            int b = tid;
            int deg = a.cnt[b]; if (deg > CAP) deg = CAP;
            sdeg2[b] = deg;
            for (int k = 0; k < deg; ++k) { se2[b][k] = a.l2e[b * CAP + k]; sp2[b][k] = k; }
            for (int a_ = 1; a_ < deg; ++a_) {
                int ke = se2[b][a_], kp = sp2[b][a_]; int c = a_ - 1;
                while (c >= 0 && se2[b][c] > ke) {
                    se2[b][c+1] = se2[b][c]; sp2[b][c+1] = sp2[b][c]; --c;
                }
                se2[b][c+1] = ke; sp2[b][c+1] = kp;
            }
            float er = a.er2[b], mx = -1e30f;
            for (int k = 0; k < deg; ++k) {
                float l = a.elog2[b * CAP + sp2[b][k]] + er;
                l = l >= 0.f ? l : NEG * l;
                sw2[b][k] = l; mx = fmaxf(mx, l);
            }
            float sum = 0.f;
            for (int k = 0; k < deg; ++k) { float p = expf(sw2[b][k] - mx); sw2[b][k] = p; sum += p; }
            float inv = sum > 0.f ? 1.f / sum : 0.f;
            for (int k = 0; k < deg; ++k) sw2[b][k] *= inv;
        }
        __syncthreads();
        int q = bid % 3, iy = bid / 3;
        int col = q * 256 + tid, i0 = iy * IC;
        for (int t = tid; t < 2 * B; t += 256) {  // stage 16 rows x 2 mats
            int r = t >> 1, mat = t & 1;
            int deg = sdeg2[r];
            float acc[IC];
            #pragma unroll
            for (int i = 0; i < IC; ++i) acc[i] = 0.f;
            if (mat == 0) {
                for (int k = 0; k < deg; ++k) {
                    const float* hs = a.h + (long)(B + r * CAP + sp2[r][k]) * D + i0;
                    float w_ = sw2[r][k];
                    #pragma unroll
                    for (int i = 0; i < IC; ++i) acc[i] += w_ * fmaxf(hs[i], 0.f);
                }
                #pragma unroll
                for (int i = 0; i < IC; ++i) sgS[r & 31][i] = acc[i];   // r<16
            } else {
                for (int k = 0; k < deg; ++k) {
                    const float* p = a.ef + (long)se2[r][k] * D + i0;
                    float w_ = sw2[r][k];
                    #pragma unroll
                    for (int i = 0; i < IC; ++i) acc[i] += w_ * p[i];
                }
                #pragma unroll
                for (int i = 0; i < IC; ++i) sgE[r & 31][i] = acc[i];
            }
        }
        __syncthreads();
        {
            float w[IC], we[IC];
            #pragma unroll
            for (int k = 0; k < IC; ++k) {
                w[k]  = a.W2[(long)(i0 + k) * D + col];
                we[k] = a.We2[(long)(i0 + k) * D + col];
            }
            for (int r = 0; r < B; ++r) {
                float acc = (iy == 0) ? fmaxf(a.h[(long)r * D + col], 0.f) + a.b2[col] : 0.f;
                #pragma unroll
                for (int k = 0; k < IC; ++k) acc += sgS[r][k] * w[k] + sgE[r][k] * we[k];
                atomicAdd(&a.out[(long)r * D + col], acc);
            }
        }
    }
}

extern "C" void kernel_launch(void* const* d_in, const int* in_sizes, int n_in,
                              void* d_out, int out_size, void* d_ws, size_t ws_size,
                              hipStream_t stream) {
    KArgs a;
    a.x    = (const float*)d_in[0];
    a.ef   = (const float*)d_in[1];
    a.src  = (const int*)d_in[2];
    a.dst  = (const int*)d_in[3];
    a.goff = (const int*)d_in[4];
    a.W1   = (const float*)d_in[5];
    a.We1  = (const float*)d_in[6];
    a.al1  = (const float*)d_in[7];
    a.ar1  = (const float*)d_in[8];
    a.ae1  = (const float*)d_in[9];
    a.b1   = (const float*)d_in[10];
    a.W2   = (const float*)d_in[11];
    a.We2  = (const float*)d_in[12];
    a.al2  = (const float*)d_in[13];
    a.ar2  = (const float*)d_in[14];
    a.ae2  = (const float*)d_in[15];
    a.b2   = (const float*)d_in[16];
    a.out  = (float*)d_out;

    a.E = in_sizes[2];
    a.B = in_sizes[4];
    a.nslot = a.B + a.B * CAP;   // 1040

    int B = a.B, nslot = a.nslot;
    int* wi = (int*)d_ws;
    a.bar   = wi;                               // 8    } zeroed by one memset
    a.cnt   = wi + 8;                           // B    }
    a.mcnt  = a.cnt + B;                        // nslot}
    a.l2e   = a.mcnt + nslot;                   // B*CAP
    a.medge = a.l2e + B * CAP;                  // nslot*MD1
    a.msrc  = a.medge + nslot * MD1;            // nslot*MD1
    a.melog = (float*)(a.msrc + nslot * MD1);   // nslot*MD1
    a.erj   = a.melog + nslot * MD1;            // nslot
    a.elog2 = a.erj + nslot;                    // B*CAP
    a.er2   = a.elog2 + B * CAP;                // B
    a.v     = a.er2 + B;                        // 6*D
    a.h     = a.v + 6 * D;                      // nslot*D

    hipMemsetAsync(a.bar, 0, (8 + B + nslot) * sizeof(int), stream);
    hipMemsetAsync(a.out, 0, (size_t)B * D * sizeof(float), stream);

    void* params[] = { &a };
    hipLaunchCooperativeKernel((void*)allfused, dim3(NBLK), dim3(256), params, 0, stream);
}

// Round 10
// 72.952 us; speedup vs baseline: 2.2247x; 2.2247x over previous
//
#include <hip/hip_runtime.h>

#define D 768
#define CAP 64        // max layer-2 in-edges per target
#define MD1 16        // max in-degree per needed node (real ~2-3)
#define NSLOTMAX 1040 // B + B*CAP (B=16)
#define VROWS 64      // cap on total valid rows (real ~48)
#define QCAP 64       // per-block eager-dot queue
#define NI 24         // i-chunks (768 = 24*32)
#define IC 32
#define NPROJ 768     // proj blocks in kA
#define NEG 0.2f

__device__ __forceinline__ float wave_reduce(float v) {
    #pragma unroll
    for (int o = 32; o > 0; o >>= 1) v += __shfl_down(v, o, 64);
    return v;
}

__device__ __forceinline__ float block_reduce_sum(float v, float* scratch) {
    int lane = threadIdx.x & 63;
    int wid  = threadIdx.x >> 6;
    v = wave_reduce(v);
    if (lane == 0) scratch[wid] = v;
    __syncthreads();
    if (threadIdx.x == 0) {
        float r = 0.f;
        #pragma unroll
        for (int w = 0; w < 4; ++w) r += scratch[w];
        scratch[0] = r;
    }
    __syncthreads();
    float r = scratch[0];
    __syncthreads();
    return r;
}

// KA: blocks [0,NPROJ): projected attention vectors; blocks [NPROJ,..): l2 edge scan
__global__ __launch_bounds__(256) void kA_proj_build(
        const float* W1, const float* We1, const float* W2, const float* We2,
        const float* al1, const float* ar1, const float* ae1,
        const float* al2, const float* ar2, const float* ae2,
        const int* __restrict__ dst, const int* __restrict__ goff,
        int E, int B, float* v, int* l2e, int* cnt) {
    int bid = blockIdx.x, tid = threadIdx.x;
    if (bid < NPROJ) {
        int task = bid * 4 + (tid >> 6);
        int lane = tid & 63;
        if (task >= 4 * D) return;
        int g = task / D, i = task % D;
        const float* W; const float* p1; const float* p2 = nullptr; int o1 = 0, o2 = 0;
        switch (g) {
            case 0: W = W1;  p1 = al1; p2 = ar1; o1 = 0;     o2 = D;     break;
            case 1: W = We1; p1 = ae1;           o1 = 2 * D;             break;
            case 2: W = W2;  p1 = al2; p2 = ar2; o1 = 3 * D; o2 = 4 * D; break;
            default:W = We2; p1 = ae2;           o1 = 5 * D;             break;
        }
        float s1 = 0.f, s2 = 0.f;
        for (int j = lane; j < D; j += 64) {
            float w = W[(long)i * D + j];
            s1 += w * p1[j];
            if (p2) s2 += w * p2[j];
        }
        #pragma unroll
        for (int o = 32; o > 0; o >>= 1) { s1 += __shfl_down(s1, o, 64); s2 += __shfl_down(s2, o, 64); }
        if (lane == 0) { v[o1 + i] = s1; if (p2) v[o2 + i] = s2; }
    } else {
        __shared__ int tg[16];
        int sb = bid - NPROJ, ns = gridDim.x - NPROJ;
        if (tid < B) tg[tid] = goff[tid];
        __syncthreads();
        for (int e = sb * 256 + tid; e < E; e += ns * 256) {
            int d = dst[e];
            for (int b = 0; b < B; ++b) {
                if (d == tg[b]) {
                    int pos = atomicAdd(&cnt[b], 1);
                    if (pos < CAP) l2e[b * CAP + pos] = e;
                }
            }
        }
    }
}

// KB: node table; er dots + h-init; match + eager logit dots; block0 writes vl
__global__ __launch_bounds__(256) void kB_match(
        const float* __restrict__ x, const float* __restrict__ ef,
        const int* __restrict__ src, const int* __restrict__ dst,
        const int* __restrict__ goff, const int* __restrict__ l2e,
        const int* __restrict__ cnt, const float* __restrict__ b1,
        const float* __restrict__ v, int E, int B, int nslot,
        int* mcnt, int* medge, int* msrc, float* melog, float* erj, float* h,
        int* vlg, int* vnp) {
    __shared__ int tnode[NSLOTMAX], tslot[NSLOTMAX];
    __shared__ int tn, qn;
    __shared__ int qe[QCAP], qs[QCAP], qsl[QCAP], qp[QCAP];
    int tid = threadIdx.x;
    if (tid == 0) { tn = 0; qn = 0; }
    __syncthreads();
    for (int s = tid; s < nslot; s += 256) {
        int node = -1; bool valid = false;
        if (s < B) { node = goff[s]; valid = true; }
        else { int rb = (s - B) >> 6, i = (s - B) & 63;
               int cb = cnt[rb]; if (cb > CAP) cb = CAP;
               if (i < cb) { node = src[l2e[rb * CAP + i]]; valid = true; } }
        if (valid) { int p = atomicAdd(&tn, 1); tnode[p] = node; tslot[p] = s; }
    }
    __syncthreads();
    int M = tn;
    const float* val1 = v;
    const float* var1 = v + D;
    const float* vae1 = v + 2 * D;
    int wv = tid >> 6, lane = tid & 63;
    // er dot + h init (one wave per slot)
    {
        int s = blockIdx.x * 4 + wv;
        if (s < nslot) {
            int j = -1; bool valid = false;
            if (s < B) { j = goff[s]; valid = true; }
            else { int rb = (s - B) >> 6, i = (s - B) & 63;
                   int cb = cnt[rb]; if (cb > CAP) cb = CAP;
                   if (i < cb) { j = src[l2e[rb * CAP + i]]; valid = true; } }
            if (valid) {
                float acc = 0.f;
                for (int c = lane; c < D; c += 64) acc += x[(long)j * D + c] * var1[c];
                acc = wave_reduce(acc);
                if (lane == 0) erj[s] = acc;
                for (int c = lane; c < D; c += 64)
                    h[(long)s * D + c] = x[(long)j * D + c] + b1[c];
            }
        }
    }
    // edge scan: append matches, queue eager dots
    for (int e = blockIdx.x * 256 + tid; e < E; e += gridDim.x * 256) {
        int d = dst[e];
        for (int c = 0; c < M; ++c) {
            if (tnode[c] == d) {
                int sl = tslot[c];
                int p = atomicAdd(&mcnt[sl], 1);
                if (p < MD1) {
                    int sr = src[e];
                    medge[sl * MD1 + p] = e;
                    msrc[sl * MD1 + p] = sr;
                    int qq = atomicAdd(&qn, 1);
                    if (qq < QCAP) { qe[qq] = e; qs[qq] = sr; qsl[qq] = sl; qp[qq] = p; }
                    else {  // rare overflow: serial dot, same value
                        float acc = 0.f;
                        for (int cc = 0; cc < D; ++cc)
                            acc += x[(long)sr * D + cc] * val1[cc] + ef[(long)e * D + cc] * vae1[cc];
                        melog[sl * MD1 + p] = acc;
                    }
                }
            }
        }
    }
    __syncthreads();
    int nq = qn; if (nq > QCAP) nq = QCAP;
    for (int m = wv; m < nq; m += 4) {
        int e = qe[m], sr = qs[m];
        float acc = 0.f;
        for (int c = lane; c < D; c += 64)
            acc += x[(long)sr * D + c] * val1[c] + ef[(long)e * D + c] * vae1[c];
        acc = wave_reduce(acc);
        if (lane == 0) melog[qsl[m] * MD1 + qp[m]] = acc;
    }
    // canonical valid-row list (deterministic ballot order), block 0 wave 0
    if (blockIdx.x == 0 && tid < 64) {
        int base = 0;
        for (int s0 = 0; s0 < nslot; s0 += 64) {
            int s = s0 + tid;
            bool valid = false;
            if (s < B) valid = true;
            else if (s < nslot) {
                int rb = (s - B) >> 6, i = (s - B) & 63;
                int cb = cnt[rb]; if (cb > CAP) cb = CAP;
                valid = i < cb;
            }
            unsigned long long mb = __ballot(valid);
            if (valid) {
                int ci = base + __popcll(mb & ((1ULL << tid) - 1));
                if (ci < VROWS) vlg[ci] = s;
            }
            base += __popcll(mb);
        }
        if (tid == 0) *vnp = base < VROWS ? base : VROWS;
    }
}

// KC: layer-1 GEMM; 2-way row split (144 blocks); single-pass stage; atomic h
__global__ __launch_bounds__(256) void kC_gemm1(
        const float* __restrict__ W1, const float* __restrict__ We1,
        const float* __restrict__ x, const float* __restrict__ ef,
        const int* __restrict__ mcnt, const int* __restrict__ medge,
        const int* __restrict__ msrc, const float* __restrict__ melog,
        const float* __restrict__ erj, const int* __restrict__ vlg,
        const int* __restrict__ vnp, float* h) {
    int tid = threadIdx.x;
    int q = blockIdx.x % 3, iy = (blockIdx.x / 3) % NI, rh = blockIdx.x / (3 * NI);
    int col = q * 256 + tid, i0 = iy * IC;
    __shared__ int vl_s[VROWS];
    __shared__ int vn_s, snm[32];
    __shared__ float smatt[32][MD1];
    __shared__ int ssrc[32][MD1], sedge[32][MD1];
    __shared__ float sgS[32][IC], sgE[32][IC];
    if (tid == 0) vn_s = *vnp;
    if (tid < VROWS) vl_s[tid] = vlg[tid];
    __syncthreads();
    int vn = vn_s;
    int half = (vn + 1) >> 1;
    int r0 = rh * half, r1 = r0 + half; if (r1 > vn) r1 = vn;
    int nr = r1 - r0;
    if (tid < nr) {  // per own row: load, sort by edge id, leaky+softmax
        int s = vl_s[r0 + tid];
        int nm = mcnt[s]; if (nm > MD1) nm = MD1;
        snm[tid] = nm;
        for (int k = 0; k < nm; ++k) {
            sedge[tid][k] = medge[s * MD1 + k];
            ssrc[tid][k]  = msrc[s * MD1 + k];
            smatt[tid][k] = melog[s * MD1 + k];
        }
        for (int a_ = 1; a_ < nm; ++a_) {
            int ke = sedge[tid][a_], ks = ssrc[tid][a_]; float kl = smatt[tid][a_];
            int b = a_ - 1;
            while (b >= 0 && sedge[tid][b] > ke) {
                sedge[tid][b+1] = sedge[tid][b]; ssrc[tid][b+1] = ssrc[tid][b];
                smatt[tid][b+1] = smatt[tid][b]; --b;
            }
            sedge[tid][b+1] = ke; ssrc[tid][b+1] = ks; smatt[tid][b+1] = kl;
        }
        float er = erj[s], mx = -1e30f;
        for (int k = 0; k < nm; ++k) {
            float l = smatt[tid][k] + er;
            l = l >= 0.f ? l : NEG * l;
            smatt[tid][k] = l; mx = fmaxf(mx, l);
        }
        float sum = 0.f;
        for (int k = 0; k < nm; ++k) { float p = expf(smatt[tid][k] - mx); smatt[tid][k] = p; sum += p; }
        float inv = 1.f / sum;
        for (int k = 0; k < nm; ++k) smatt[tid][k] *= inv;
    }
    __syncthreads();
    // single-pass stage: task t = (local row, mat); 2*nr <= 64 <= 256 threads
    if (tid < 2 * nr) {
        int lr = tid >> 1, mat = tid & 1;
        int nm = snm[lr];
        float acc[IC];
        #pragma unroll
        for (int i = 0; i < IC; ++i) acc[i] = 0.f;
        if (mat == 0) {
            for (int k = 0; k < nm; ++k) {
                const float* p = x + (long)ssrc[lr][k] * D + i0;
                float w_ = smatt[lr][k];
                #pragma unroll
                for (int i = 0; i < IC; ++i) acc[i] += w_ * p[i];
            }
            #pragma unroll
            for (int i = 0; i < IC; ++i) sgS[lr][i] = acc[i];
        } else {
            for (int k = 0; k < nm; ++k) {
                const float* p = ef + (long)sedge[lr][k] * D + i0;
                float w_ = smatt[lr][k];
                #pragma unroll
                for (int i = 0; i < IC; ++i) acc[i] += w_ * p[i];
            }
            #pragma unroll
            for (int i = 0; i < IC; ++i) sgE[lr][i] = acc[i];
        }
    }
    __syncthreads();
    if (nr > 0) {
        float w[IC], we[IC];
        #pragma unroll
        for (int k = 0; k < IC; ++k) {
            w[k]  = W1[(long)(i0 + k) * D + col];
            we[k] = We1[(long)(i0 + k) * D + col];
        }
        for (int lr = 0; lr < nr; ++lr) {
            float acc = 0.f;
            #pragma unroll
            for (int k = 0; k < IC; ++k) acc += sgS[lr][k] * w[k] + sgE[lr][k] * we[k];
            atomicAdd(&h[(long)vl_s[r0 + lr] * D + col], acc);
        }
    }
}

// KD: layer-2 logit dots on relu(h) + er2 + out-init (wave per task)
__global__ __launch_bounds__(256) void kD_l2prep(
        const float* __restrict__ ef, const int* __restrict__ l2e,
        const int* __restrict__ cnt, const float* __restrict__ b2,
        const float* __restrict__ v, const float* __restrict__ h,
        float* elog2, float* er2, float* out, int B, int nslot) {
    int wv = threadIdx.x >> 6, lane = threadIdx.x & 63;
    int t = blockIdx.x * 4 + wv;
    const float* val2 = v + 3 * D;
    const float* var2 = v + 4 * D;
    const float* vae2 = v + 5 * D;
    if (t < B) {
        float acc = 0.f;
        for (int c = lane; c < D; c += 64) acc += fmaxf(h[(long)t * D + c], 0.f) * var2[c];
        acc = wave_reduce(acc);
        if (lane == 0) er2[t] = acc;
        for (int c = lane; c < D; c += 64)
            out[(long)t * D + c] = fmaxf(h[(long)t * D + c], 0.f) + b2[c];
    } else if (t < nslot) {
        int rb = (t - B) >> 6, i = (t - B) & 63;
        int cb = cnt[rb]; if (cb > CAP) cb = CAP;
        if (i < cb) {
            int e = l2e[rb * CAP + i];
            const float* hs = h + (long)t * D;
            float acc = 0.f;
            for (int c = lane; c < D; c += 64)
                acc += fmaxf(hs[c], 0.f) * val2[c] + ef[(long)e * D + c] * vae2[c];
            acc = wave_reduce(acc);
            if (lane == 0) elog2[rb * CAP + i] = acc;
        }
    }
}

// KE: layer-2 GEMM; per-block scalar softmax, single-pass stage, atomic out
__global__ __launch_bounds__(256) void kE_gemm2(
        const float* __restrict__ W2, const float* __restrict__ We2,
        const float* __restrict__ ef, const int* __restrict__ l2e,
        const int* __restrict__ cnt, const float* __restrict__ elog2,
        const float* __restrict__ er2, const float* __restrict__ h,
        float* out, int B) {
    __shared__ float smatt[16][CAP];
    __shared__ int sedge[16][CAP], spos[16][CAP], sdeg[16];
    __shared__ float sgS[16][IC], sgE[16][IC];
    int tid = threadIdx.x;
    int q = blockIdx.x % 3, iy = blockIdx.x / 3;
    int col = q * 256 + tid, i0 = iy * IC;
    if (tid < B) {
        int b = tid;
        int deg = cnt[b]; if (deg > CAP) deg = CAP;
        sdeg[b] = deg;
        for (int k = 0; k < deg; ++k) { sedge[b][k] = l2e[b * CAP + k]; spos[b][k] = k; }
        for (int a_ = 1; a_ < deg; ++a_) {
            int ke = sedge[b][a_], kp = spos[b][a_]; int c = a_ - 1;
            while (c >= 0 && sedge[b][c] > ke) {
                sedge[b][c+1] = sedge[b][c]; spos[b][c+1] = spos[b][c]; --c;
            }
            sedge[b][c+1] = ke; spos[b][c+1] = kp;
        }
        float er = er2[b], mx = -1e30f;
        for (int k = 0; k < deg; ++k) {
            float l = elog2[b * CAP + spos[b][k]] + er;
            l = l >= 0.f ? l : NEG * l;
            smatt[b][k] = l; mx = fmaxf(mx, l);
        }
        float sum = 0.f;
        for (int k = 0; k < deg; ++k) { float p = expf(smatt[b][k] - mx); smatt[b][k] = p; sum += p; }
        float inv = sum > 0.f ? 1.f / sum : 0.f;
        for (int k = 0; k < deg; ++k) smatt[b][k] *= inv;
    }
    __syncthreads();
    // single-pass stage: 2*B = 32 tasks <= 256 threads
    if (tid < 2 * B) {
        int r = tid >> 1, mat = tid & 1;
        int deg = sdeg[r];
        float acc[IC];
        #pragma unroll
        for (int i = 0; i < IC; ++i) acc[i] = 0.f;
        if (mat == 0) {
            for (int k = 0; k < deg; ++k) {
                const float* hs = h + (long)(B + r * CAP + spos[r][k]) * D + i0;
                float w_ = smatt[r][k];
                #pragma unroll
                for (int i = 0; i < IC; ++i) acc[i] += w_ * fmaxf(hs[i], 0.f);
            }
            #pragma unroll
            for (int i = 0; i < IC; ++i) sgS[r][i] = acc[i];
        } else {
            for (int k = 0; k < deg; ++k) {
                const float* p = ef + (long)sedge[r][k] * D + i0;
                float w_ = smatt[r][k];
                #pragma unroll
                for (int i = 0; i < IC; ++i) acc[i] += w_ * p[i];
            }
            #pragma unroll
            for (int i = 0; i < IC; ++i) sgE[r][i] = acc[i];
        }
    }
    __syncthreads();
    {
        float w[IC], we[IC];
        #pragma unroll
        for (int k = 0; k < IC; ++k) {
            w[k]  = W2[(long)(i0 + k) * D + col];
            we[k] = We2[(long)(i0 + k) * D + col];
        }
        for (int r = 0; r < B; ++r) {
            float acc = 0.f;
            #pragma unroll
            for (int k = 0; k < IC; ++k) acc += sgS[r][k] * w[k] + sgE[r][k] * we[k];
            atomicAdd(&out[(long)r * D + col], acc);
        }
    }
}

extern "C" void kernel_launch(void* const* d_in, const int* in_sizes, int n_in,
                              void* d_out, int out_size, void* d_ws, size_t ws_size,
                              hipStream_t stream) {
    const float* x    = (const float*)d_in[0];
    const float* ef   = (const float*)d_in[1];
    const int*   src  = (const int*)d_in[2];
    const int*   dst  = (const int*)d_in[3];
    const int*   goff = (const int*)d_in[4];
    const float* W1   = (const float*)d_in[5];
    const float* We1  = (const float*)d_in[6];
    const float* al1  = (const float*)d_in[7];
    const float* ar1  = (const float*)d_in[8];
    const float* ae1  = (const float*)d_in[9];
    const float* b1   = (const float*)d_in[10];
    const float* W2   = (const float*)d_in[11];
    const float* We2  = (const float*)d_in[12];
    const float* al2  = (const float*)d_in[13];
    const float* ar2  = (const float*)d_in[14];
    const float* ae2  = (const float*)d_in[15];
    const float* b2   = (const float*)d_in[16];
    float* out = (float*)d_out;

    int E = in_sizes[2];
    int B = in_sizes[4];
    int nslot = B + B * CAP;   // 1040

    float* ws    = (float*)d_ws;
    float* v     = ws;                            // 6*D
    int*   l2e   = (int*)(v + 6 * D);             // B*CAP
    int*   cnt   = l2e + B * CAP;                 // B      } zeroed by memset
    int*   mcnt  = cnt + B;                       // nslot  }
    int*   medge = mcnt + nslot;                  // nslot*MD1
    int*   msrc  = medge + nslot * MD1;           // nslot*MD1
    float* melog = (float*)(msrc + nslot * MD1);  // nslot*MD1
    float* erj   = melog + nslot * MD1;           // nslot
    int*   vlg   = (int*)(erj + nslot);           // VROWS
    int*   vnp   = vlg + VROWS;                   // 1
    float* elog2 = (float*)(vnp + 1);             // B*CAP
    float* er2   = elog2 + B * CAP;               // B
    float* h     = er2 + B;                       // nslot*D

    int egrid = (E + 255) / 256;

    hipMemsetAsync(cnt, 0, (size_t)(B + nslot) * sizeof(int), stream);
    hipLaunchKernelGGL(kA_proj_build, dim3(NPROJ + egrid), dim3(256), 0, stream,
                       W1, We1, W2, We2, al1, ar1, ae1, al2, ar2, ae2,
                       dst, goff, E, B, v, l2e, cnt);
    hipLaunchKernelGGL(kB_match, dim3(egrid), dim3(256), 0, stream,
                       x, ef, src, dst, goff, l2e, cnt, b1, v, E, B, nslot,
                       mcnt, medge, msrc, melog, erj, h, vlg, vnp);
    hipLaunchKernelGGL(kC_gemm1, dim3(3 * NI * 2), dim3(256), 0, stream,
                       W1, We1, x, ef, mcnt, medge, msrc, melog, erj, vlg, vnp, h);
    hipLaunchKernelGGL(kD_l2prep, dim3((nslot + 3) / 4), dim3(256), 0, stream,
                       ef, l2e, cnt, b2, v, h, elog2, er2, out, B, nslot);
    hipLaunchKernelGGL(kE_gemm2, dim3(3 * NI), dim3(256), 0, stream,
                       W2, We2, ef, l2e, cnt, elog2, er2, h, out, B);
}